// Round 18
// baseline (180.560 us; speedup 1.0000x reference)
//
#include <hip/hip_runtime.h>
#include <hip/hip_bf16.h>
#include <math.h>

#define N_TOKENS 16384
#define DIM      4096
#define NE       64
#define TOPK     8
#define NCHUNK   13     // OpenBLAS Kc blocks: [320 x 11, 288, 288]
#define BK1      16     // 64B x-rows (coalesced); 320=20*16, 288=18*16
#define NT1      (N_TOKENS / 64)    // 256 tiles of 64 tokens -> grid 3328

// HBM -> LDS direct. aux=0 normal; aux=2 (NT) for streaming x so it does
// not evict the reused w slice from L2 (r15/r16: FETCH 440->243 MB).
__device__ __forceinline__ void gld16(const float* g, float* l) {
    __builtin_amdgcn_global_load_lds(
        (const __attribute__((address_space(1))) void*)g,
        (__attribute__((address_space(3))) void*)l, 16, 0, 0);
}
__device__ __forceinline__ void gld16nt(const float* g, float* l) {
    __builtin_amdgcn_global_load_lds(
        (const __attribute__((address_space(1))) void*)g,
        (__attribute__((address_space(3))) void*)l, 16, 0, 2);
}

// ---------------- Pass 1: one OpenBLAS K-chunk per block.y ----------------
// part[b][token][expert]. r17 ledger: VALUBusy 44% == the issue floor; the
// 2.2x duration gap is per-wave LDS-latency exposure (xv ds_read -> FMA
// distance ~64 issue-cyc < 120cy latency). This round: explicit register
// software-pipeline — wf prefetched one kq ahead (512-cyc FMA phase hides
// it), xv one i ahead. Parity indices are compile-time (&1 of unrolled
// vars). Skeleton unchanged from r17: 1-wave blocks, 16KB LDS (10/CU),
// NT-x + cached-w LDS dbuf, stage-then-vmcnt(8), zero barriers, no
// occupancy attribute (r13/r15: waves_per_eu shaves VGPR -> spills).
__global__ __launch_bounds__(64) void gate_pass1(
    const float* __restrict__ x, const float* __restrict__ w, float* __restrict__ part)
{
    __shared__ float xs[2][64 * BK1];   // 2 x 4 KB
    __shared__ float ws[2][BK1 * NE];   // 2 x 4 KB

    const int lane = threadIdx.x & 63;
    const int eg   = lane & 7;           // expert group (8 experts)
    const int tg   = lane >> 3;          // token base 0..7
    const int e0   = eg * 8;
    const int g0   = blockIdx.x * 64;
    const int b    = blockIdx.y;
    const int kstart = (b < 12) ? 320 * b : 3808;
    const int nsteps = (b < 11) ? 20 : 18;

    float acc[8][8];
#pragma unroll
    for (int i = 0; i < 8; ++i)
#pragma unroll
        for (int j = 0; j < 8; ++j) acc[i][j] = 0.0f;

    // Staging geometry (per-lane, constant).
    const int xrow = lane >> 2;                 // row within a 16-row call
    const int c4s  = (lane & 3) ^ (xrow & 3);   // pre-swizzled float4 col (rule #21)
    const int wrow = lane >> 4;                 // 0..3
    const int wc4  = lane & 15;

    auto stage = [&](int buf, int k0) {
#pragma unroll
        for (int q = 0; q < 4; ++q) {   // x (streaming: NT)
            const float* src = x + (size_t)(g0 + q * 16 + xrow) * DIM + k0 + c4s * 4;
            gld16nt(src, &xs[buf][(q * 16) * BK1]);
        }
#pragma unroll
        for (int q = 0; q < 4; ++q) {   // w (reused across blocks: keep cached)
            const float* src = w + (size_t)(k0 + q * 4 + wrow) * NE + wc4 * 4;
            gld16(src, &ws[buf][q * 4 * NE]);
        }
    };

    stage(0, kstart);
    int cur = 0;
    const int tg3 = tg & 3;
    for (int s = 0; s < nsteps; ++s) {
        if (s + 1 < nsteps) {
            stage(cur ^ 1, kstart + BK1 * (s + 1));          // newest 8 in flight
            asm volatile("s_waitcnt vmcnt(8)" ::: "memory"); // previous 8 landed
        } else {
            asm volatile("s_waitcnt vmcnt(0)" ::: "memory");
        }
        __builtin_amdgcn_sched_barrier(0);

        float wf[2][4][8];   // double-buffered w fragments (parity = kq&1)
        float xv[2][4];      // double-buffered x row (parity = i&1)

        // Preload kq=0 wf and (kq=0, i=0) xv.
#pragma unroll
        for (int kk = 0; kk < 4; ++kk) {
            *reinterpret_cast<float4*>(&wf[0][kk][0]) =
                *reinterpret_cast<const float4*>(&ws[cur][kk * NE + e0]);
            *reinterpret_cast<float4*>(&wf[0][kk][4]) =
                *reinterpret_cast<const float4*>(&ws[cur][kk * NE + e0 + 4]);
        }
        *reinterpret_cast<float4*>(xv[0]) =
            *reinterpret_cast<const float4*>(&xs[cur][tg * BK1 + (0 ^ tg3) * 4]);

#pragma unroll
        for (int kq = 0; kq < 4; ++kq) {
            const int cb  = kq & 1;
            const int kqs = (kq ^ tg3) * 4;   // un-swizzle on read
            if (kq < 3) {                     // prefetch next kq's w fragment
#pragma unroll
                for (int kk = 0; kk < 4; ++kk) {
                    *reinterpret_cast<float4*>(&wf[cb ^ 1][kk][0]) =
                        *reinterpret_cast<const float4*>(&ws[cur][((kq + 1) * 4 + kk) * NE + e0]);
                    *reinterpret_cast<float4*>(&wf[cb ^ 1][kk][4]) =
                        *reinterpret_cast<const float4*>(&ws[cur][((kq + 1) * 4 + kk) * NE + e0 + 4]);
                }
            }
#pragma unroll
            for (int i = 0; i < 8; ++i) {
                const int ci = i & 1;
                if (i < 7) {                  // prefetch next token row
                    *reinterpret_cast<float4*>(xv[ci ^ 1]) =
                        *reinterpret_cast<const float4*>(&xs[cur][(tg + 8 * (i + 1)) * BK1 + kqs]);
                } else if (kq < 3) {          // first row of next kq
                    *reinterpret_cast<float4*>(xv[ci ^ 1]) =
                        *reinterpret_cast<const float4*>(&xs[cur][tg * BK1 + ((kq + 1) ^ tg3) * 4]);
                }
                // Per (token i, expert j): kk 0..3, kq 0..3, steps ascend
                // -> strictly ascending k within the chunk (exact BLAS chain).
#pragma unroll
                for (int kk = 0; kk < 4; ++kk)
#pragma unroll
                    for (int j = 0; j < 8; ++j)
                        acc[i][j] = fmaf(xv[ci][kk], wf[cb][kk][j], acc[i][j]);
            }
        }
        cur ^= 1;
    }

    float* pt = part + ((size_t)b * N_TOKENS + g0) * NE;
#pragma unroll
    for (int i = 0; i < 8; ++i) {
        *reinterpret_cast<float4*>(&pt[(tg + 8 * i) * NE + e0]) =
            *reinterpret_cast<float4*>(&acc[i][0]);
        *reinterpret_cast<float4*>(&pt[(tg + 8 * i) * NE + e0 + 4]) =
            *reinterpret_cast<float4*>(&acc[i][4]);
    }
}

// ------- Pass 2: fold 13 partials ascending (exact ref tree) + epilogue -------
// 2048 blocks x 4 waves; each wave = 2 tokens, lane = expert.
__global__ __launch_bounds__(256) void gate_pass2(
    const float* __restrict__ part, float* __restrict__ out)
{
    const int tid  = threadIdx.x;
    const int lane = tid & 63;
    const int wid  = tid >> 6;
    float* outI = out;
    float* outG = out + (size_t)N_TOKENS * TOPK;

#pragma unroll
    for (int tt = 0; tt < 2; ++tt) {
        const int g = blockIdx.x * 8 + wid * 2 + tt;

        // left-fold ascending b: ((B0+B1)+...)+B12  (0+B0 == B0 bit-exactly)
        float v = 0.0f;
#pragma unroll
        for (int bb = 0; bb < NCHUNK; ++bb)
            v += part[((size_t)bb * N_TOKENS + g) * NE + lane];

        float m = v;
#pragma unroll
        for (int off = 32; off; off >>= 1) m = fmaxf(m, __shfl_xor(m, off));
        float e = expf(v - m);
        float ssum = e;
#pragma unroll
        for (int off = 32; off; off >>= 1) ssum += __shfl_xor(ssum, off);
        float gte = e / ssum;

        // top-8 on logits (monotone == gate rank), ties -> lower index
        float curv = v;
        const int idx = lane;
        float myi = 0.0f, myg = 0.0f;
#pragma unroll
        for (int r = 0; r < TOPK; ++r) {
            float bv = curv;
            int   bi = idx;
#pragma unroll
            for (int off = 32; off; off >>= 1) {
                float ov = __shfl_xor(bv, off);
                int   oi = __shfl_xor(bi, off);
                if (ov > bv || (ov == bv && oi < bi)) { bv = ov; bi = oi; }
            }
            float wgv = __shfl(gte, bi);
            if (lane == r) { myi = (float)bi; myg = wgv; }
            if (idx == bi) curv = -INFINITY;
        }
        if (lane < TOPK) {
            outI[(size_t)g * TOPK + lane] = myi;
            outG[(size_t)g * TOPK + lane] = myg;
        }
    }
}

// ---------------- Fallback: verified single-pass round-5 kernel ----------------
#define TM 64
#define BK 64
#define XS_STRIDE 68
__global__ __launch_bounds__(256) void topk_gating_blas(
    const float* __restrict__ x, const float* __restrict__ w, float* __restrict__ out)
{
    __shared__ float xs[TM * XS_STRIDE];
    __shared__ float ws[BK * NE];

    const int tid = threadIdx.x;
    const int eg  = tid & 15;
    const int tg  = tid >> 4;
    const int e0  = eg * 4;
    const int t0  = tg * 4;
    const int bt0 = blockIdx.x * TM;

    float acc[4][4], tot[4][4];
#pragma unroll
    for (int i = 0; i < 4; ++i)
#pragma unroll
        for (int j = 0; j < 4; ++j) { acc[i][j] = 0.0f; tot[i][j] = 0.0f; }

    const float4* xg = reinterpret_cast<const float4*>(x);
    const float4* wg = reinterpret_cast<const float4*>(w);
    float4 xr[4], wr[4];

    auto load_step = [&](int k0) {
#pragma unroll
        for (int r = 0; r < 4; ++r) {
            int idx = tid + 256 * r;
            int T = idx >> 4, c = idx & 15;
            xr[r] = xg[(size_t)(bt0 + T) * (DIM / 4) + (k0 >> 2) + c];
            wr[r] = wg[(size_t)(k0 + T) * (NE / 4) + c];
        }
    };
    auto write_step = [&]() {
#pragma unroll
        for (int r = 0; r < 4; ++r) {
            int idx = tid + 256 * r;
            int T = idx >> 4, c = idx & 15;
            *reinterpret_cast<float4*>(&xs[T * XS_STRIDE + c * 4]) = xr[r];
            *reinterpret_cast<float4*>(&ws[T * NE + c * 4])        = wr[r];
        }
    };
    auto fold = [&]() {
#pragma unroll
        for (int i = 0; i < 4; ++i)
#pragma unroll
            for (int j = 0; j < 4; ++j) { tot[i][j] += acc[i][j]; acc[i][j] = 0.0f; }
    };

    load_step(0);
    for (int s = 0; s < DIM / BK; ++s) {
        __syncthreads();
        write_step();
        __syncthreads();
        if (s + 1 < DIM / BK) load_step((s + 1) * BK);
#pragma unroll
        for (int kq = 0; kq < 16; ++kq) {
            float xf[4][4], wf[4][4];
#pragma unroll
            for (int i = 0; i < 4; ++i)
                *reinterpret_cast<float4*>(xf[i]) =
                    *reinterpret_cast<const float4*>(&xs[(t0 + i) * XS_STRIDE + kq * 4]);
#pragma unroll
            for (int kk = 0; kk < 4; ++kk)
                *reinterpret_cast<float4*>(wf[kk]) =
                    *reinterpret_cast<const float4*>(&ws[(kq * 4 + kk) * NE + e0]);
#pragma unroll
            for (int kk = 0; kk < 4; ++kk)
#pragma unroll
                for (int i = 0; i < 4; ++i)
#pragma unroll
                    for (int j = 0; j < 4; ++j)
                        acc[i][j] = fmaf(xf[i][kk], wf[kk][j], acc[i][j]);
            if (kq == 7 && s == 59) fold();
        }
        if ((s % 5) == 4 && s <= 54) fold();
    }
    fold();

    __syncthreads();
#pragma unroll
    for (int i = 0; i < 4; ++i)
        *reinterpret_cast<float4*>(&xs[(t0 + i) * XS_STRIDE + e0]) =
            *reinterpret_cast<float4*>(tot[i]);
    __syncthreads();

    const int lane = tid & 63;
    const int wid  = tid >> 6;
    float* outI = out;
    float* outG = out + (size_t)N_TOKENS * TOPK;

    for (int tt = 0; tt < 16; ++tt) {
        const int t = wid * 16 + tt;
        float v = xs[t * XS_STRIDE + lane];
        float m = v;
#pragma unroll
        for (int off = 32; off; off >>= 1) m = fmaxf(m, __shfl_xor(m, off));
        float e = expf(v - m);
        float ssum = e;
#pragma unroll
        for (int off = 32; off; off >>= 1) ssum += __shfl_xor(ssum, off);
        float g = e / ssum;

        float curv = v;
        const int idx = lane;
        float myi = 0.0f, myg = 0.0f;
#pragma unroll
        for (int r = 0; r < TOPK; ++r) {
            float bv = curv;
            int   bi = idx;
#pragma unroll
            for (int off = 32; off; off >>= 1) {
                float ov = __shfl_xor(bv, off);
                int   oi = __shfl_xor(bi, off);
                if (ov > bv || (ov == bv && oi < bi)) { bv = ov; bi = oi; }
            }
            float wgv = __shfl(g, bi);
            if (lane == r) { myi = (float)bi; myg = wgv; }
            if (idx == bi) curv = -INFINITY;
        }
        const int gt = bt0 + t;
        if (lane < TOPK) {
            outI[(size_t)gt * TOPK + lane] = myi;
            outG[(size_t)gt * TOPK + lane] = myg;
        }
    }
}

extern "C" void kernel_launch(void* const* d_in, const int* in_sizes, int n_in,
                              void* d_out, int out_size, void* d_ws, size_t ws_size,
                              hipStream_t stream) {
    const float* x = (const float*)d_in[0];
    const float* w = (const float*)d_in[1];
    float* out = (float*)d_out;
    const size_t needed = (size_t)NCHUNK * N_TOKENS * NE * sizeof(float);  // 54.5 MB
    if (ws_size >= needed) {
        float* part = (float*)d_ws;
        gate_pass1<<<dim3(NT1, NCHUNK), dim3(64), 0, stream>>>(x, w, part);
        gate_pass2<<<dim3(N_TOKENS / 8), dim3(256), 0, stream>>>(part, out);
    } else {
        topk_gating_blas<<<dim3(N_TOKENS / TM), dim3(256), 0, stream>>>(x, w, out);
    }
}

// Round 19
// 172.707 us; speedup vs baseline: 1.0455x; 1.0455x over previous
//
#include <hip/hip_runtime.h>
#include <hip/hip_bf16.h>
#include <math.h>

#define N_TOKENS 16384
#define DIM      4096
#define NE       64
#define TOPK     8
#define NCHUNK   13     // OpenBLAS Kc blocks: [320 x 11, 288, 288]
#define BK1      16     // 64B x-rows (coalesced); 320=20*16, 288=18*16
#define TW1      32     // tokens per wave (12KB/wave -> 13 waves/CU, 2 clean phases)
#define NT1      (N_TOKENS / TW1)   // 512 tiles -> grid 6656 1-wave blocks

// HBM -> LDS direct. aux=0 normal; aux=2 (NT) for streaming x so it does
// not evict the reused w slice from L2 (r15/r16: FETCH 440->243 MB).
__device__ __forceinline__ void gld16(const float* g, float* l) {
    __builtin_amdgcn_global_load_lds(
        (const __attribute__((address_space(1))) void*)g,
        (__attribute__((address_space(3))) void*)l, 16, 0, 0);
}
__device__ __forceinline__ void gld16nt(const float* g, float* l) {
    __builtin_amdgcn_global_load_lds(
        (const __attribute__((address_space(1))) void*)g,
        (__attribute__((address_space(3))) void*)l, 16, 0, 2);
}

// ---------------- Pass 1: one OpenBLAS K-chunk per block.y ----------------
// part[b][token][expert]. r16 vs r17 tied (both 10 waves/CU, 16KB/wave):
// occupancy 16% = phase quantization (13 blocks over 10 slots -> half the
// kernel at 3-block fill). This round: 32 tok/wave -> 12KB/wave -> 13
// waves/CU, grid 26 blocks/CU = TWO FULL phases (no ragged tail).
// Micro-tile 4 tok x 8 exp. Pipeline unchanged from r17: NT-x + cached-w
// wave-private LDS dbuf, stage-then-vmcnt(6), zero barriers, no occupancy
// attribute (r13/r15: waves_per_eu shaves VGPR below live -> spills).
__global__ __launch_bounds__(64) void gate_pass1(
    const float* __restrict__ x, const float* __restrict__ w, float* __restrict__ part)
{
    __shared__ float xs[2][TW1 * BK1];  // 2 x 2 KB
    __shared__ float ws[2][BK1 * NE];   // 2 x 4 KB

    const int lane = threadIdx.x & 63;
    const int eg   = lane & 7;           // expert group (8 experts)
    const int tg   = lane >> 3;          // token base 0..7
    const int e0   = eg * 8;
    const int g0   = blockIdx.x * TW1;
    const int b    = blockIdx.y;
    const int kstart = (b < 12) ? 320 * b : 3808;
    const int nsteps = (b < 11) ? 20 : 18;

    float acc[4][8];
#pragma unroll
    for (int i = 0; i < 4; ++i)
#pragma unroll
        for (int j = 0; j < 8; ++j) acc[i][j] = 0.0f;

    // Staging geometry (per-lane, constant).
    const int xrow = lane >> 2;                 // row within a 16-row call
    const int c4s  = (lane & 3) ^ (xrow & 3);   // pre-swizzled float4 col (rule #21)
    const int wrow = lane >> 4;                 // 0..3
    const int wc4  = lane & 15;

    auto stage = [&](int buf, int k0) {
#pragma unroll
        for (int q = 0; q < 2; ++q) {   // x: rows q*16..+15 (streaming: NT)
            const float* src = x + (size_t)(g0 + q * 16 + xrow) * DIM + k0 + c4s * 4;
            gld16nt(src, &xs[buf][(q * 16) * BK1]);
        }
#pragma unroll
        for (int q = 0; q < 4; ++q) {   // w: rows q*4..+3 (keep cached)
            const float* src = w + (size_t)(k0 + q * 4 + wrow) * NE + wc4 * 4;
            gld16(src, &ws[buf][q * 4 * NE]);
        }
    };

    stage(0, kstart);
    int cur = 0;
    const int tg3 = tg & 3;
    for (int s = 0; s < nsteps; ++s) {
        if (s + 1 < nsteps) {
            stage(cur ^ 1, kstart + BK1 * (s + 1));          // newest 6 in flight
            asm volatile("s_waitcnt vmcnt(6)" ::: "memory"); // previous 6 landed
        } else {
            asm volatile("s_waitcnt vmcnt(0)" ::: "memory");
        }
        __builtin_amdgcn_sched_barrier(0);

#pragma unroll
        for (int kq = 0; kq < 4; ++kq) {
            float wf[4][8];   // 4 k-values x 8 experts (2-way banks = free)
#pragma unroll
            for (int kk = 0; kk < 4; ++kk) {
                *reinterpret_cast<float4*>(&wf[kk][0]) =
                    *reinterpret_cast<const float4*>(&ws[cur][(kq * 4 + kk) * NE + e0]);
                *reinterpret_cast<float4*>(&wf[kk][4]) =
                    *reinterpret_cast<const float4*>(&ws[cur][(kq * 4 + kk) * NE + e0 + 4]);
            }
            const int kqs = (kq ^ tg3) * 4;   // un-swizzle on read (row&3 == tg&3)
            // Per (token i, expert j): kk 0..3, kq 0..3, steps ascend
            // -> strictly ascending k within the chunk (exact BLAS chain).
#pragma unroll
            for (int i = 0; i < 4; ++i) {
                float xv[4];   // 8 lanes (same tg) share addr -> LDS broadcast
                *reinterpret_cast<float4*>(xv) =
                    *reinterpret_cast<const float4*>(&xs[cur][(tg + 8 * i) * BK1 + kqs]);
#pragma unroll
                for (int kk = 0; kk < 4; ++kk)
#pragma unroll
                    for (int j = 0; j < 8; ++j)
                        acc[i][j] = fmaf(xv[kk], wf[kk][j], acc[i][j]);
            }
        }
        cur ^= 1;
    }

    float* pt = part + ((size_t)b * N_TOKENS + g0) * NE;
#pragma unroll
    for (int i = 0; i < 4; ++i) {
        *reinterpret_cast<float4*>(&pt[(tg + 8 * i) * NE + e0]) =
            *reinterpret_cast<float4*>(&acc[i][0]);
        *reinterpret_cast<float4*>(&pt[(tg + 8 * i) * NE + e0 + 4]) =
            *reinterpret_cast<float4*>(&acc[i][4]);
    }
}

// ------- Pass 2: fold 13 partials ascending (exact ref tree) + epilogue -------
// 1024 blocks x 4 waves x 4 tokens/wave; 16-lane group per token, float4
// loads (1KB/wave-instr). Fold ascending bb per expert (bit-exact chain);
// ranking on bit-exact logits with lower-index ties (order-independent).
__global__ __launch_bounds__(256) void gate_pass2(
    const float* __restrict__ part, float* __restrict__ out)
{
    const int tid  = threadIdx.x;
    const int lane = tid & 63;
    const int wid  = tid >> 6;
    const int sub  = lane >> 4;        // token within wave (0..3)
    const int sl   = lane & 15;        // lane within 16-group = float4 col
    const int g    = blockIdx.x * 16 + wid * 4 + sub;
    float* outI = out;
    float* outG = out + (size_t)N_TOKENS * TOPK;

    const float4* p4 = reinterpret_cast<const float4*>(part);
    float4 v = make_float4(0.f, 0.f, 0.f, 0.f);
#pragma unroll
    for (int bb = 0; bb < NCHUNK; ++bb) {   // ascending: ((B0+B1)+...)+B12
        float4 p = p4[((size_t)bb * N_TOKENS + g) * (NE / 4) + sl];
        v.x += p.x; v.y += p.y; v.z += p.z; v.w += p.w;
    }

    // softmax (16-lane group reduces; xor masks 1..8 stay within group)
    float m = fmaxf(fmaxf(v.x, v.y), fmaxf(v.z, v.w));
#pragma unroll
    for (int off = 1; off <= 8; off <<= 1) m = fmaxf(m, __shfl_xor(m, off));
    float4 ex;
    ex.x = expf(v.x - m); ex.y = expf(v.y - m);
    ex.z = expf(v.z - m); ex.w = expf(v.w - m);
    float ssum = ex.x + ex.y + ex.z + ex.w;
#pragma unroll
    for (int off = 1; off <= 8; off <<= 1) ssum += __shfl_xor(ssum, off);
    float4 gt4;
    gt4.x = ex.x / ssum; gt4.y = ex.y / ssum;
    gt4.z = ex.z / ssum; gt4.w = ex.w / ssum;

    // top-8 on logits, ties -> lower index
    float4 cv = v;
    float myi = 0.0f, myg = 0.0f;
#pragma unroll
    for (int r = 0; r < TOPK; ++r) {
        float bv = cv.x; int bc = 0;              // local best, lowest comp on tie
        if (cv.y > bv) { bv = cv.y; bc = 1; }
        if (cv.z > bv) { bv = cv.z; bc = 2; }
        if (cv.w > bv) { bv = cv.w; bc = 3; }
        int bi = sl * 4 + bc;
#pragma unroll
        for (int off = 1; off <= 8; off <<= 1) {
            float ov = __shfl_xor(bv, off);
            int   oi = __shfl_xor(bi, off);
            if (ov > bv || (ov == bv && oi < bi)) { bv = ov; bi = oi; }
        }
        const int wc = bi & 3;                    // uniform within group
        float cand = (wc == 0) ? gt4.x : (wc == 1) ? gt4.y : (wc == 2) ? gt4.z : gt4.w;
        float gw = __shfl(cand, (lane & 48) | (bi >> 2));
        if (sl == r) { myi = (float)bi; myg = gw; }
        if ((bi >> 2) == sl) {                    // owner clears winner comp
            if (wc == 0) cv.x = -INFINITY; else if (wc == 1) cv.y = -INFINITY;
            else if (wc == 2) cv.z = -INFINITY; else cv.w = -INFINITY;
        }
    }
    if (sl < TOPK) {
        outI[(size_t)g * TOPK + sl] = myi;
        outG[(size_t)g * TOPK + sl] = myg;
    }
}

// ---------------- Fallback: verified single-pass round-5 kernel ----------------
#define TM 64
#define BK 64
#define XS_STRIDE 68
__global__ __launch_bounds__(256) void topk_gating_blas(
    const float* __restrict__ x, const float* __restrict__ w, float* __restrict__ out)
{
    __shared__ float xs[TM * XS_STRIDE];
    __shared__ float ws[BK * NE];

    const int tid = threadIdx.x;
    const int eg  = tid & 15;
    const int tg  = tid >> 4;
    const int e0  = eg * 4;
    const int t0  = tg * 4;
    const int bt0 = blockIdx.x * TM;

    float acc[4][4], tot[4][4];
#pragma unroll
    for (int i = 0; i < 4; ++i)
#pragma unroll
        for (int j = 0; j < 4; ++j) { acc[i][j] = 0.0f; tot[i][j] = 0.0f; }

    const float4* xg = reinterpret_cast<const float4*>(x);
    const float4* wg = reinterpret_cast<const float4*>(w);
    float4 xr[4], wr[4];

    auto load_step = [&](int k0) {
#pragma unroll
        for (int r = 0; r < 4; ++r) {
            int idx = tid + 256 * r;
            int T = idx >> 4, c = idx & 15;
            xr[r] = xg[(size_t)(bt0 + T) * (DIM / 4) + (k0 >> 2) + c];
            wr[r] = wg[(size_t)(k0 + T) * (NE / 4) + c];
        }
    };
    auto write_step = [&]() {
#pragma unroll
        for (int r = 0; r < 4; ++r) {
            int idx = tid + 256 * r;
            int T = idx >> 4, c = idx & 15;
            *reinterpret_cast<float4*>(&xs[T * XS_STRIDE + c * 4]) = xr[r];
            *reinterpret_cast<float4*>(&ws[T * NE + c * 4])        = wr[r];
        }
    };
    auto fold = [&]() {
#pragma unroll
        for (int i = 0; i < 4; ++i)
#pragma unroll
            for (int j = 0; j < 4; ++j) { tot[i][j] += acc[i][j]; acc[i][j] = 0.0f; }
    };

    load_step(0);
    for (int s = 0; s < DIM / BK; ++s) {
        __syncthreads();
        write_step();
        __syncthreads();
        if (s + 1 < DIM / BK) load_step((s + 1) * BK);
#pragma unroll
        for (int kq = 0; kq < 16; ++kq) {
            float xf[4][4], wf[4][4];
#pragma unroll
            for (int i = 0; i < 4; ++i)
                *reinterpret_cast<float4*>(xf[i]) =
                    *reinterpret_cast<const float4*>(&xs[(t0 + i) * XS_STRIDE + kq * 4]);
#pragma unroll
            for (int kk = 0; kk < 4; ++kk)
                *reinterpret_cast<float4*>(wf[kk]) =
                    *reinterpret_cast<const float4*>(&ws[(kq * 4 + kk) * NE + e0]);
#pragma unroll
            for (int kk = 0; kk < 4; ++kk)
#pragma unroll
                for (int i = 0; i < 4; ++i)
#pragma unroll
                    for (int j = 0; j < 4; ++j)
                        acc[i][j] = fmaf(xf[i][kk], wf[kk][j], acc[i][j]);
            if (kq == 7 && s == 59) fold();
        }
        if ((s % 5) == 4 && s <= 54) fold();
    }
    fold();

    __syncthreads();
#pragma unroll
    for (int i = 0; i < 4; ++i)
        *reinterpret_cast<float4*>(&xs[(t0 + i) * XS_STRIDE + e0]) =
            *reinterpret_cast<float4*>(tot[i]);
    __syncthreads();

    const int lane = tid & 63;
    const int wid  = tid >> 6;
    float* outI = out;
    float* outG = out + (size_t)N_TOKENS * TOPK;

    for (int tt = 0; tt < 16; ++tt) {
        const int t = wid * 16 + tt;
        float v = xs[t * XS_STRIDE + lane];
        float m = v;
#pragma unroll
        for (int off = 32; off; off >>= 1) m = fmaxf(m, __shfl_xor(m, off));
        float e = expf(v - m);
        float ssum = e;
#pragma unroll
        for (int off = 32; off; off >>= 1) ssum += __shfl_xor(ssum, off);
        float g = e / ssum;

        float curv = v;
        const int idx = lane;
        float myi = 0.0f, myg = 0.0f;
#pragma unroll
        for (int r = 0; r < TOPK; ++r) {
            float bv = curv;
            int   bi = idx;
#pragma unroll
            for (int off = 32; off; off >>= 1) {
                float ov = __shfl_xor(bv, off);
                int   oi = __shfl_xor(bi, off);
                if (ov > bv || (ov == bv && oi < bi)) { bv = ov; bi = oi; }
            }
            float wgv = __shfl(g, bi);
            if (lane == r) { myi = (float)bi; myg = wgv; }
            if (idx == bi) curv = -INFINITY;
        }
        const int gt = bt0 + t;
        if (lane < TOPK) {
            outI[(size_t)gt * TOPK + lane] = myi;
            outG[(size_t)gt * TOPK + lane] = myg;
        }
    }
}

extern "C" void kernel_launch(void* const* d_in, const int* in_sizes, int n_in,
                              void* d_out, int out_size, void* d_ws, size_t ws_size,
                              hipStream_t stream) {
    const float* x = (const float*)d_in[0];
    const float* w = (const float*)d_in[1];
    float* out = (float*)d_out;
    const size_t needed = (size_t)NCHUNK * N_TOKENS * NE * sizeof(float);  // 54.5 MB
    if (ws_size >= needed) {
        float* part = (float*)d_ws;
        gate_pass1<<<dim3(NT1, NCHUNK), dim3(64), 0, stream>>>(x, w, part);
        gate_pass2<<<dim3(N_TOKENS / 16), dim3(256), 0, stream>>>(part, out);
    } else {
        topk_gating_blas<<<dim3(N_TOKENS / TM), dim3(256), 0, stream>>>(x, w, out);
    }
}